// Round 5
// baseline (268.772 us; speedup 1.0000x reference)
//
#include <hip/hip_runtime.h>
#include <hip/hip_bf16.h>

// MultiHeadAttention B=2,S=2048,D=1024,H=16,Dh=64. fp32 I/O, bf16 MFMA compute.
// R5: attn split-keys x2 (1024 blocks, 4/CU) + additive partial merge;
// gemm_out split-K x2 with fp32 unsafeAtomicAdd epilogue; single fused cvt.

typedef short bf16x8 __attribute__((ext_vector_type(8)));
typedef short bf16x4 __attribute__((ext_vector_type(4)));
typedef float f32x4  __attribute__((ext_vector_type(4)));

constexpr size_t NE = (size_t)4096 * 1024;   // elems of [B*S, D]
constexpr size_t NW = (size_t)1024 * 1024;   // elems of [D, D]
constexpr size_t NL = (size_t)4096 * 16;     // l entries per half: (B*S)*H

#define EXP2(x) exp2f(x)

__device__ __forceinline__ short f2bf(float f) {
  __hip_bfloat16 h = __float2bfloat16(f);
  return *reinterpret_cast<short*>(&h);
}
__device__ __forceinline__ float bf2f(short s) {
  __hip_bfloat16 h = *reinterpret_cast<__hip_bfloat16*>(&s);
  return __bfloat162float(h);
}

__device__ __forceinline__ void cp16(const short* g, short* l) {
  __builtin_amdgcn_global_load_lds(
      (const __attribute__((address_space(1))) void*)g,
      (__attribute__((address_space(3))) void*)l, 16, 0, 0);
}

// ---------------- fused fp32 -> bf16 conversion, 16 slices of 1M elems
__global__ __launch_bounds__(256) void cvt_kernel(
    const float* q, const float* k, const float* v,
    const float* Wq, const float* Wk, const float* Wv, const float* Wo,
    short* qb, short* kb, short* vb,
    short* Wqb, short* Wkb, short* Wvb, short* Wob) {
  const int y = blockIdx.y;
  const float* s; short* d;
  if (y < 12) {
    const int t = y >> 2;
    const size_t off = (size_t)(y & 3) << 20;
    s = (t == 0 ? q : (t == 1 ? k : v)) + off;
    d = (t == 0 ? qb : (t == 1 ? kb : vb)) + off;
  } else {
    s = (y == 12 ? Wq : (y == 13 ? Wk : (y == 14 ? Wv : Wo)));
    d = (y == 12 ? Wqb : (y == 13 ? Wkb : (y == 14 ? Wvb : Wob)));
  }
  size_t i = (size_t)blockIdx.x * 256 + threadIdx.x;
  float4 val = ((const float4*)s)[i];
  bf16x4 o;
  o[0] = f2bf(val.x); o[1] = f2bf(val.y); o[2] = f2bf(val.z); o[3] = f2bf(val.w);
  ((bf16x4*)d)[i] = o;
}

// ---------------- fused Q/K/V projection GEMM: C = (A @ W^T + b) * scale
// 128x128 tile, BK=32, global_load_lds 16B, 4 waves of 64x64.
// which=0: Q scaled by 0.125*log2(e); which=1: K; which=2: V -> [b,h,dh,s].
__global__ __launch_bounds__(256) void gemm_qkv(
    const short* __restrict__ A0, const short* __restrict__ A1, const short* __restrict__ A2,
    const short* __restrict__ W0, const short* __restrict__ W1, const short* __restrict__ W2,
    const float* __restrict__ b0, const float* __restrict__ b1, const float* __restrict__ b2,
    short* __restrict__ C0, short* __restrict__ C1, short* __restrict__ Cv) {
  __shared__ short As[128 * 32];
  __shared__ short Bs[128 * 32];
  const int which = blockIdx.y;
  const short* A    = which == 0 ? A0 : (which == 1 ? A1 : A2);
  const short* W    = which == 0 ? W0 : (which == 1 ? W1 : W2);
  const float* bias = which == 0 ? b0 : (which == 1 ? b1 : b2);
  const float scale = which == 0 ? 0.18033688011112042f : 1.0f;  // 0.125*log2e

  const int tid  = threadIdx.x;
  const int bm   = (int)blockIdx.x >> 3;
  const int bn   = (int)blockIdx.x & 7;
  const int lane = tid & 63, wid = tid >> 6;
  const int g = lane >> 4, l15 = lane & 15;
  const int wm = (wid >> 1) * 64, wn = (wid & 1) * 64;

  const short* Ag = A + (size_t)(bm * 128 + (tid >> 2)) * 1024 + (tid & 3) * 8;
  const short* Wg = W + (size_t)(bn * 128 + (tid >> 2)) * 1024 + (tid & 3) * 8;
  short* AsW = As + wid * 512;
  short* BsW = Bs + wid * 512;

  f32x4 acc[4][4];
#pragma unroll
  for (int i = 0; i < 4; ++i)
#pragma unroll
    for (int j = 0; j < 4; ++j) acc[i][j] = (f32x4){0.f, 0.f, 0.f, 0.f};

  for (int k0 = 0; k0 < 1024; k0 += 32) {
    __syncthreads();
    cp16(Ag + k0,             AsW);
    cp16(Ag + 64 * 1024 + k0, AsW + 2048);
    cp16(Wg + k0,             BsW);
    cp16(Wg + 64 * 1024 + k0, BsW + 2048);
    __syncthreads();

    bf16x8 af[4], bf[4];
#pragma unroll
    for (int mt = 0; mt < 4; ++mt)
      af[mt] = *(const bf16x8*)&As[(wm + mt * 16 + l15) * 32 + g * 8];
#pragma unroll
    for (int nt = 0; nt < 4; ++nt)
      bf[nt] = *(const bf16x8*)&Bs[(wn + nt * 16 + l15) * 32 + g * 8];
#pragma unroll
    for (int mt = 0; mt < 4; ++mt)
#pragma unroll
      for (int nt = 0; nt < 4; ++nt)
        acc[mt][nt] = __builtin_amdgcn_mfma_f32_16x16x32_bf16(
            af[mt], bf[nt], acc[mt][nt], 0, 0, 0);
  }

  const int col0 = bn * 128 + wn;
  if (which < 2) {
    short* C = which == 0 ? C0 : C1;
#pragma unroll
    for (int nt = 0; nt < 4; ++nt) {
      const int col = col0 + nt * 16 + l15;
      const float bb = bias[col];
#pragma unroll
      for (int mt = 0; mt < 4; ++mt) {
        const int m0 = bm * 128 + wm + mt * 16 + g * 4;
#pragma unroll
        for (int r = 0; r < 4; ++r)
          C[(size_t)(m0 + r) * 1024 + col] = f2bf((acc[mt][nt][r] + bb) * scale);
      }
    }
  } else {
#pragma unroll
    for (int nt = 0; nt < 4; ++nt) {
      const int col = col0 + nt * 16 + l15;
      const int h = col >> 6, dh = col & 63;
      const float bb = bias[col];
#pragma unroll
      for (int mt = 0; mt < 4; ++mt) {
        const int m0 = bm * 128 + wm + mt * 16 + g * 4;   // 4-aligned, same b
        const int bb_ = m0 >> 11, s0 = m0 & 2047;
        bf16x4 o;
#pragma unroll
        for (int r = 0; r < 4; ++r) o[r] = f2bf(acc[mt][nt][r] + bb);
        *(bf16x4*)&Cv[(((size_t)bb_ * 16 + h) * 64 + dh) * 2048 + s0] = o;
      }
    }
  }
}

// ---------------- output projection GEMM, split-K x2, atomic fp32 epilogue
__global__ __launch_bounds__(256) void gemm_out(
    const short* __restrict__ A, const short* __restrict__ W,
    const float* __restrict__ bias, float* __restrict__ C) {
  __shared__ short As[128 * 32];
  __shared__ short Bs[128 * 32];
  const int tid  = threadIdx.x;
  const int bm   = (int)blockIdx.x >> 3;
  const int bn   = (int)blockIdx.x & 7;
  const int kh   = blockIdx.y;             // 0/1: K half
  const int lane = tid & 63, wid = tid >> 6;
  const int g = lane >> 4, l15 = lane & 15;
  const int wm = (wid >> 1) * 64, wn = (wid & 1) * 64;

  const short* Ag = A + (size_t)(bm * 128 + (tid >> 2)) * 1024 + (tid & 3) * 8;
  const short* Wg = W + (size_t)(bn * 128 + (tid >> 2)) * 1024 + (tid & 3) * 8;
  short* AsW = As + wid * 512;
  short* BsW = Bs + wid * 512;

  f32x4 acc[4][4];
#pragma unroll
  for (int i = 0; i < 4; ++i)
#pragma unroll
    for (int j = 0; j < 4; ++j) acc[i][j] = (f32x4){0.f, 0.f, 0.f, 0.f};

  for (int k0 = kh * 512; k0 < kh * 512 + 512; k0 += 32) {
    __syncthreads();
    cp16(Ag + k0,             AsW);
    cp16(Ag + 64 * 1024 + k0, AsW + 2048);
    cp16(Wg + k0,             BsW);
    cp16(Wg + 64 * 1024 + k0, BsW + 2048);
    __syncthreads();

    bf16x8 af[4], bf[4];
#pragma unroll
    for (int mt = 0; mt < 4; ++mt)
      af[mt] = *(const bf16x8*)&As[(wm + mt * 16 + l15) * 32 + g * 8];
#pragma unroll
    for (int nt = 0; nt < 4; ++nt)
      bf[nt] = *(const bf16x8*)&Bs[(wn + nt * 16 + l15) * 32 + g * 8];
#pragma unroll
    for (int mt = 0; mt < 4; ++mt)
#pragma unroll
      for (int nt = 0; nt < 4; ++nt)
        acc[mt][nt] = __builtin_amdgcn_mfma_f32_16x16x32_bf16(
            af[mt], bf[nt], acc[mt][nt], 0, 0, 0);
  }

  const int col0 = bn * 128 + wn;
#pragma unroll
  for (int nt = 0; nt < 4; ++nt) {
    const int col = col0 + nt * 16 + l15;
    const float bb = kh == 0 ? bias[col] : 0.f;
#pragma unroll
    for (int mt = 0; mt < 4; ++mt) {
      const int m0 = bm * 128 + wm + mt * 16 + g * 4;
#pragma unroll
      for (int r = 0; r < 4; ++r)
        unsafeAtomicAdd(&C[(size_t)(m0 + r) * 1024 + col], acc[mt][nt][r] + bb);
    }
  }
}

// ---------------- flash attention, static-max exp2 softmax, split-keys x2.
// Each wg handles 16 of 32 key-tiles; writes unnormalized O (bf16) + l (fp32).
__global__ __launch_bounds__(256) void attn_kernel(
    const short* __restrict__ Q, const short* __restrict__ K,
    const short* __restrict__ Vg, short* __restrict__ Op, float* __restrict__ Lp) {
  __shared__ short Kt[64][72];      // [key][dh]
  __shared__ short Vt[64][72];      // [dh][key]
  __shared__ short Pt[4][32][72];   // per-wave [qrow][key]

  const int tid  = threadIdx.x;
  const int qt   = (int)blockIdx.x & 15;          // 16 q-tiles
  const int bh   = ((int)blockIdx.x >> 4) & 31;   // 32 (b,h)
  const int half = (int)blockIdx.x >> 9;          // 0/1: key half
  const int b    = bh >> 4, h = bh & 15;
  const int lane = tid & 63, wid = tid >> 6;
  const int g = lane >> 4, l15 = lane & 15;

  const int q0 = qt * 128 + wid * 32;
  bf16x8 qf[2][2];
#pragma unroll
  for (int mt = 0; mt < 2; ++mt) {
    const size_t base = (size_t)(b * 2048 + q0 + mt * 16 + l15) * 1024 + h * 64;
    qf[mt][0] = *(const bf16x8*)(Q + base + g * 8);
    qf[mt][1] = *(const bf16x8*)(Q + base + 32 + g * 8);
  }

  f32x4 o_acc[2][4];
#pragma unroll
  for (int i = 0; i < 2; ++i)
#pragma unroll
    for (int j = 0; j < 4; ++j) o_acc[i][j] = (f32x4){0.f, 0.f, 0.f, 0.f};
  float l_i[2][4];
#pragma unroll
  for (int i = 0; i < 2; ++i)
#pragma unroll
    for (int r = 0; r < 4; ++r) l_i[i][r] = 0.f;

  const int srow = tid >> 2, sch = tid & 3;
  const short* Kbase = K + (size_t)(b * 2048) * 1024 + h * 64 + sch * 8;
  const short* Vbase = Vg + (size_t)((b * 16 + h) * 64 + srow) * 2048 + sch * 8;

  for (int kt = half * 16; kt < half * 16 + 16; ++kt) {
    __syncthreads();
    {
      const short* krow = Kbase + (size_t)(kt * 64 + srow) * 1024;
      *(bf16x8*)&Kt[srow][sch * 8]      = *(const bf16x8*)(krow);
      *(bf16x8*)&Kt[srow][sch * 8 + 32] = *(const bf16x8*)(krow + 32);
      *(bf16x8*)&Vt[srow][sch * 8]      = *(const bf16x8*)(Vbase + kt * 64);
      *(bf16x8*)&Vt[srow][sch * 8 + 32] = *(const bf16x8*)(Vbase + kt * 64 + 32);
    }
    __syncthreads();

    f32x4 sv[2][4];
#pragma unroll
    for (int nt = 0; nt < 4; ++nt) {
      bf16x8 kf0 = *(const bf16x8*)&Kt[nt * 16 + l15][g * 8];
      bf16x8 kf1 = *(const bf16x8*)&Kt[nt * 16 + l15][32 + g * 8];
#pragma unroll
      for (int mt = 0; mt < 2; ++mt) {
        f32x4 z = (f32x4){0.f, 0.f, 0.f, 0.f};
        z = __builtin_amdgcn_mfma_f32_16x16x32_bf16(qf[mt][0], kf0, z, 0, 0, 0);
        z = __builtin_amdgcn_mfma_f32_16x16x32_bf16(qf[mt][1], kf1, z, 0, 0, 0);
        sv[mt][nt] = z;
      }
    }

#pragma unroll
    for (int mt = 0; mt < 2; ++mt)
#pragma unroll
      for (int r = 0; r < 4; ++r) {
        float p0 = EXP2(sv[mt][0][r]);
        float p1 = EXP2(sv[mt][1][r]);
        float p2 = EXP2(sv[mt][2][r]);
        float p3 = EXP2(sv[mt][3][r]);
        l_i[mt][r] += (p0 + p1) + (p2 + p3);
        const int pr = mt * 16 + g * 4 + r;
        Pt[wid][pr][l15]      = f2bf(p0);
        Pt[wid][pr][16 + l15] = f2bf(p1);
        Pt[wid][pr][32 + l15] = f2bf(p2);
        Pt[wid][pr][48 + l15] = f2bf(p3);
      }
    // no barrier: Pt slab is wave-private; per-wave DS ops execute in order

    bf16x8 pf[2][2];
#pragma unroll
    for (int mt = 0; mt < 2; ++mt) {
      pf[mt][0] = *(const bf16x8*)&Pt[wid][mt * 16 + l15][g * 8];
      pf[mt][1] = *(const bf16x8*)&Pt[wid][mt * 16 + l15][32 + g * 8];
    }
#pragma unroll
    for (int nt = 0; nt < 4; ++nt) {
      bf16x8 vf0 = *(const bf16x8*)&Vt[nt * 16 + l15][g * 8];
      bf16x8 vf1 = *(const bf16x8*)&Vt[nt * 16 + l15][32 + g * 8];
#pragma unroll
      for (int mt = 0; mt < 2; ++mt) {
        o_acc[mt][nt] = __builtin_amdgcn_mfma_f32_16x16x32_bf16(
            pf[mt][0], vf0, o_acc[mt][nt], 0, 0, 0);
        o_acc[mt][nt] = __builtin_amdgcn_mfma_f32_16x16x32_bf16(
            pf[mt][1], vf1, o_acc[mt][nt], 0, 0, 0);
      }
    }
  }

  // epilogue: write unnormalized O (bf16) + per-row l (fp32) partials
#pragma unroll
  for (int mt = 0; mt < 2; ++mt)
#pragma unroll
    for (int r = 0; r < 4; ++r) {
      float l = l_i[mt][r];
#pragma unroll
      for (int off = 1; off < 16; off <<= 1) l += __shfl_xor(l, off, 64);
      const int row = q0 + mt * 16 + g * 4 + r;
      const size_t bs = (size_t)(b * 2048 + row);
      if (l15 == 0) Lp[half * NL + bs * 16 + h] = l;
      const size_t base = half * NE + bs * 1024 + h * 64;
#pragma unroll
      for (int nt = 0; nt < 4; ++nt)
        Op[base + nt * 16 + l15] = f2bf(o_acc[mt][nt][r]);
    }
}

// ---------------- merge the two key-half partials: Ob = (O0+O1)/(l0+l1)
__global__ __launch_bounds__(256) void merge_kernel(
    const short* __restrict__ Op, const float* __restrict__ Lp,
    short* __restrict__ Ob) {
  const size_t i8 = ((size_t)blockIdx.x * 256 + threadIdx.x) * 8;
  const size_t bs = i8 >> 10;
  const int h = (int)((i8 & 1023) >> 6);
  const float inv = 1.0f / (Lp[bs * 16 + h] + Lp[NL + bs * 16 + h]);
  bf16x8 o0 = *(const bf16x8*)(Op + i8);
  bf16x8 o1 = *(const bf16x8*)(Op + NE + i8);
  bf16x8 o;
#pragma unroll
  for (int j = 0; j < 8; ++j) o[j] = f2bf((bf2f(o0[j]) + bf2f(o1[j])) * inv);
  *(bf16x8*)(Ob + i8) = o;
}

extern "C" void kernel_launch(void* const* d_in, const int* in_sizes, int n_in,
                              void* d_out, int out_size, void* d_ws, size_t ws_size,
                              hipStream_t stream) {
  (void)in_sizes; (void)n_in; (void)out_size; (void)ws_size;
  const float* q  = (const float*)d_in[0];
  const float* k  = (const float*)d_in[1];
  const float* v  = (const float*)d_in[2];
  const float* Wq = (const float*)d_in[3];
  const float* bq = (const float*)d_in[4];
  const float* Wk = (const float*)d_in[5];
  const float* bk = (const float*)d_in[6];
  const float* Wv = (const float*)d_in[7];
  const float* bv = (const float*)d_in[8];
  const float* Wo = (const float*)d_in[9];
  const float* bo = (const float*)d_in[10];
  float* out = (float*)d_out;

  short* qb  = (short*)d_ws;       // bf16 inputs
  short* kb  = qb + NE;
  short* vb  = kb + NE;
  short* Wqb = vb + NE;            // bf16 weights
  short* Wkb = Wqb + NW;
  short* Wvb = Wkb + NW;
  short* Wob = Wvb + NW;
  short* Qw  = Wob + NW;           // projected Q (pre-scaled)
  short* Kw  = Qw + NE;
  short* Vtg = Kw + NE;            // projected V [b,h,dh,s]
  // dead-region reuse after gemm_qkv:
  short* Op  = kb;                 // attn partial O, 2*NE bf16 (kb+vb region)
  float* Lp  = (float*)Wqb;        // attn partial l, 2*NL fp32 (512 KB)
  short* Ob  = qb;                 // merged attention out (gemm_out input)

  cvt_kernel<<<dim3(1024, 16), 256, 0, stream>>>(q, k, v, Wq, Wk, Wv, Wo,
                                                 qb, kb, vb, Wqb, Wkb, Wvb, Wob);
  gemm_qkv<<<dim3(256, 3), 256, 0, stream>>>(qb, kb, vb, Wqb, Wkb, Wvb,
                                             bq, bk, bv, Qw, Kw, Vtg);
  attn_kernel<<<1024, 256, 0, stream>>>(Qw, Kw, Vtg, Op, Lp);
  merge_kernel<<<2048, 256, 0, stream>>>(Op, Lp, Ob);
  hipMemsetAsync(out, 0, (size_t)out_size * sizeof(float), stream);
  gemm_out<<<dim3(256, 2), 256, 0, stream>>>(Ob, Wob, bo, out);
}